// Round 2
// baseline (1136.229 us; speedup 1.0000x reference)
//
#include <hip/hip_runtime.h>

#define N_NODES 100000
#define N_EDGES 1600000
#define C_H     128
#define C_OUT   40
#define K_FC    384
#define BN_EPS  1e-5f
#define NB      391        // buckets: row >> 8
#define CHUNK   6144       // edges per binning workgroup

typedef unsigned int uint;

// ---------------------------------------------------------------- utilities
__global__ void zero_i32(int* p, int n) {
    int i = blockIdx.x * blockDim.x + threadIdx.x;
    if (i < n) p[i] = 0;
}

// -------- CSR build, stage 1: per-chunk LDS histogram over 391 buckets
__global__ __launch_bounds__(256) void bucket_count(const int* __restrict__ erow,
                                                    int* __restrict__ bcnt) {
    __shared__ int cnt[NB];
    for (int i = threadIdx.x; i < NB; i += 256) cnt[i] = 0;
    __syncthreads();
    const int c0 = blockIdx.x * CHUNK;
    const int c1 = min(c0 + CHUNK, N_EDGES);
    for (int e = c0 + threadIdx.x; e < c1; e += 256)
        atomicAdd(&cnt[erow[e] >> 8], 1);
    __syncthreads();
    for (int i = threadIdx.x; i < NB; i += 256)
        if (cnt[i]) atomicAdd(&bcnt[i], cnt[i]);
}

// -------- stage 2: exclusive scan of bucket counts (single WG)
__global__ __launch_bounds__(256) void scan_buckets(const int* __restrict__ bcnt,
                                                    int* __restrict__ bstart,
                                                    int* __restrict__ bfill) {
    __shared__ int sa[512], sb[512];
    const int t = threadIdx.x;
    int v0 = (t < NB) ? bcnt[t] : 0;
    int v1 = (t + 256 < NB) ? bcnt[t + 256] : 0;
    sa[t] = v0; sa[t + 256] = v1;
    __syncthreads();
    int* src = sa; int* dst = sb;
    for (int off = 1; off < 512; off <<= 1) {
        dst[t]       = src[t]       + (t >= off ? src[t - off] : 0);
        dst[t + 256] = src[t + 256] + (t + 256 >= off ? src[t + 256 - off] : 0);
        __syncthreads();
        int* tmp = src; src = dst; dst = tmp;
    }
    if (t < NB)       { bstart[t] = src[t] - v0;             bfill[t] = src[t] - v0; }
    if (t + 256 < NB) { bstart[t + 256] = src[t + 256] - v1; bfill[t + 256] = src[t + 256] - v1; }
    if (t == 0) bstart[NB] = N_EDGES;
}

// -------- stage 3: scatter (row,col) pairs into per-bucket dense ranges
__global__ __launch_bounds__(256) void bucket_bin(const int* __restrict__ erow,
                                                  const int* __restrict__ ecol,
                                                  int* __restrict__ bfill,
                                                  int2* __restrict__ pairs) {
    __shared__ int cnt[NB];
    __shared__ int lpos[NB];
    for (int i = threadIdx.x; i < NB; i += 256) cnt[i] = 0;
    __syncthreads();
    const int c0 = blockIdx.x * CHUNK;
    const int c1 = min(c0 + CHUNK, N_EDGES);
    for (int e = c0 + threadIdx.x; e < c1; e += 256)
        atomicAdd(&cnt[erow[e] >> 8], 1);
    __syncthreads();
    for (int i = threadIdx.x; i < NB; i += 256)
        lpos[i] = cnt[i] ? atomicAdd(&bfill[i], cnt[i]) : 0;
    __syncthreads();
    for (int e = c0 + threadIdx.x; e < c1; e += 256) {
        int r = erow[e], c = ecol[e];
        int p = atomicAdd(&lpos[r >> 8], 1);
        pairs[p] = make_int2(r, c);
    }
}

// -------- stage 4: per-bucket local sort -> rowptr, dinv, cols (one WG/bucket)
__global__ __launch_bounds__(256) void bucket_csr(const int2* __restrict__ pairs,
                                                  const int* __restrict__ bstart,
                                                  int* __restrict__ rowptr,
                                                  float* __restrict__ dinv,
                                                  int* __restrict__ colsg) {
    __shared__ int lcnt[256], sa[256], sb[256], lpos[256];
    const int b = blockIdx.x;
    const int t = threadIdx.x;
    const int p0 = bstart[b], p1 = bstart[b + 1];
    lcnt[t] = 0;
    __syncthreads();
    for (int i = p0 + t; i < p1; i += 256)
        atomicAdd(&lcnt[pairs[i].x & 255], 1);
    __syncthreads();
    sa[t] = lcnt[t];
    __syncthreads();
    int* src = sa; int* dst = sb;
    for (int off = 1; off < 256; off <<= 1) {
        dst[t] = src[t] + (t >= off ? src[t - off] : 0);
        __syncthreads();
        int* tmp = src; src = dst; dst = tmp;
    }
    const int excl = src[t] - lcnt[t];
    const int r = b * 256 + t;
    if (r < N_NODES) {
        rowptr[r] = p0 + excl;
        dinv[r] = rsqrtf((float)lcnt[t] + 1.0f);
    }
    if (b == NB - 1 && t == 0) rowptr[N_NODES] = N_EDGES;
    lpos[t] = excl;
    __syncthreads();
    for (int i = p0 + t; i < p1; i += 256) {
        int2 pr = pairs[i];
        int s = atomicAdd(&lpos[pr.x & 255], 1);
        colsg[p0 + s] = pr.y;
    }
}

// relu(bn(agg + b)) = relu(agg*s + t)
__global__ void bn_coef(const float* b1, const float* g1, const float* be1,
                        const float* m1, const float* v1,
                        const float* b2, const float* g2, const float* be2,
                        const float* m2, const float* v2,
                        float* s1, float* t1, float* s2, float* t2) {
    int f = threadIdx.x;
    float sa = g1[f] * rsqrtf(v1[f] + BN_EPS);
    s1[f] = sa;
    t1[f] = (b1[f] - m1[f]) * sa + be1[f];
    float sb = g2[f] * rsqrtf(v2[f] + BN_EPS);
    s2[f] = sb;
    t2[f] = (b2[f] - m2[f]) * sb + be2[f];
}

#define FMA4(A, S, V) \
    A.x = fmaf(S, V.x, A.x); A.y = fmaf(S, V.y, A.y); \
    A.z = fmaf(S, V.z, A.z); A.w = fmaf(S, V.w, A.w);

__device__ inline uint pack_bf16x2(float a, float b) {
    uint ua = __builtin_bit_cast(uint, a);
    uint ub = __builtin_bit_cast(uint, b);
    ua += 0x7fffu + ((ua >> 16) & 1u);   // RNE
    ub += 0x7fffu + ((ub >> 16) & 1u);
    return (ua >> 16) | (ub & 0xffff0000u);
}

// -------------------- GEMM + dinv prescale: Hs(bf16) = diag(dinv) * (X @ W)
__global__ __launch_bounds__(256) void gemm_scaled(const float* __restrict__ X,
                                                   const float* __restrict__ W,
                                                   const float* __restrict__ dinv,
                                                   uint* __restrict__ Hs) {
    __shared__ float wl[64 * 128];   // k-half of W  (32 KB)
    __shared__ float xl[32 * 68];    // 32 rows x 64 cols, stride 68

    const int tid = threadIdx.x;
    const int rg = tid >> 5;
    const int c4 = (tid & 31) << 2;
    const int rb = blockIdx.x * 32;
    const int r0 = rb + rg * 4;

    float4 acc0 = {0,0,0,0}, acc1 = {0,0,0,0}, acc2 = {0,0,0,0}, acc3 = {0,0,0,0};

    for (int half = 0; half < 2; ++half) {
        const int k0 = half * 64;
        __syncthreads();
        {
            const float4* W4 = (const float4*)(W + (size_t)k0 * 128);
            float4* wl4 = (float4*)wl;
            #pragma unroll
            for (int i = 0; i < 8; ++i) wl4[tid + i * 256] = W4[tid + i * 256];
        }
        #pragma unroll
        for (int i = 0; i < 2; ++i) {
            int f = tid + i * 256;
            int row = f >> 4, cc = f & 15;
            float4 v = *(const float4*)(X + (size_t)(rb + row) * 128 + k0 + cc * 4);
            *(float4*)&xl[row * 68 + cc * 4] = v;
        }
        __syncthreads();

        for (int k4 = 0; k4 < 16; ++k4) {
            const float* wr = wl + k4 * 4 * 128 + c4;
            float4 w0 = *(const float4*)(wr);
            float4 w1 = *(const float4*)(wr + 128);
            float4 w2 = *(const float4*)(wr + 256);
            float4 w3 = *(const float4*)(wr + 384);
            float4 xv0 = *(const float4*)&xl[(rg * 4 + 0) * 68 + k4 * 4];
            float4 xv1 = *(const float4*)&xl[(rg * 4 + 1) * 68 + k4 * 4];
            float4 xv2 = *(const float4*)&xl[(rg * 4 + 2) * 68 + k4 * 4];
            float4 xv3 = *(const float4*)&xl[(rg * 4 + 3) * 68 + k4 * 4];
            FMA4(acc0, xv0.x, w0) FMA4(acc0, xv0.y, w1) FMA4(acc0, xv0.z, w2) FMA4(acc0, xv0.w, w3)
            FMA4(acc1, xv1.x, w0) FMA4(acc1, xv1.y, w1) FMA4(acc1, xv1.z, w2) FMA4(acc1, xv1.w, w3)
            FMA4(acc2, xv2.x, w0) FMA4(acc2, xv2.y, w1) FMA4(acc2, xv2.z, w2) FMA4(acc2, xv2.w, w3)
            FMA4(acc3, xv3.x, w0) FMA4(acc3, xv3.y, w1) FMA4(acc3, xv3.z, w2) FMA4(acc3, xv3.w, w3)
        }
    }
    float d0 = dinv[r0], d1 = dinv[r0 + 1], d2 = dinv[r0 + 2], d3 = dinv[r0 + 3];
    uint2 o;
    o.x = pack_bf16x2(acc0.x * d0, acc0.y * d0);
    o.y = pack_bf16x2(acc0.z * d0, acc0.w * d0);
    *(uint2*)(Hs + (size_t)(r0 + 0) * 64 + (c4 >> 1)) = o;
    o.x = pack_bf16x2(acc1.x * d1, acc1.y * d1);
    o.y = pack_bf16x2(acc1.z * d1, acc1.w * d1);
    *(uint2*)(Hs + (size_t)(r0 + 1) * 64 + (c4 >> 1)) = o;
    o.x = pack_bf16x2(acc2.x * d2, acc2.y * d2);
    o.y = pack_bf16x2(acc2.z * d2, acc2.w * d2);
    *(uint2*)(Hs + (size_t)(r0 + 2) * 64 + (c4 >> 1)) = o;
    o.x = pack_bf16x2(acc3.x * d3, acc3.y * d3);
    o.y = pack_bf16x2(acc3.z * d3, acc3.w * d3);
    *(uint2*)(Hs + (size_t)(r0 + 3) * 64 + (c4 >> 1)) = o;
}

// -------------------- SpMM on prescaled bf16 Hs: one wave per row, 2ch/lane.
// 16-deep gather pipeline, then 4, then 1.
#define ACC1(V) \
    accx += __builtin_bit_cast(float, V << 16); \
    accy += __builtin_bit_cast(float, V & 0xffff0000u);

__global__ __launch_bounds__(256) void spmm_bn_relu4(
    const uint* __restrict__ Hs, const int* __restrict__ cols,
    const int* __restrict__ rowptr, const float* __restrict__ dinv,
    const float* __restrict__ s, const float* __restrict__ t,
    float* __restrict__ Y) {
    const int lane = threadIdx.x & 63;
    const int r = blockIdx.x * 4 + (threadIdx.x >> 6);

    uint vself = Hs[(size_t)r * 64 + lane];
    float accx = __builtin_bit_cast(float, vself << 16);
    float accy = __builtin_bit_cast(float, vself & 0xffff0000u);
    const float di = dinv[r];
    const int e0 = rowptr[r], e1 = rowptr[r + 1];
    int j = e0;
    const int n16 = e0 + ((e1 - e0) & ~15);
    for (; j < n16; j += 16) {
        uint v[16];
        #pragma unroll
        for (int q = 0; q < 16; ++q)
            v[q] = Hs[(size_t)cols[j + q] * 64 + lane];
        #pragma unroll
        for (int q = 0; q < 16; ++q) { ACC1(v[q]) }
    }
    const int n4 = e0 + ((e1 - e0) & ~3);
    for (; j < n4; j += 4) {
        uint v[4];
        #pragma unroll
        for (int q = 0; q < 4; ++q)
            v[q] = Hs[(size_t)cols[j + q] * 64 + lane];
        #pragma unroll
        for (int q = 0; q < 4; ++q) { ACC1(v[q]) }
    }
    for (; j < e1; ++j) {
        uint v0 = Hs[(size_t)cols[j] * 64 + lane];
        ACC1(v0)
    }
    float2 sf = ((const float2*)s)[lane];
    float2 tf = ((const float2*)t)[lane];
    float2 o;
    o.x = fmaxf(fmaf(accx * di, sf.x, tf.x), 0.0f);
    o.y = fmaxf(fmaf(accy * di, sf.y, tf.y), 0.0f);
    ((float2*)Y)[(size_t)r * 64 + lane] = o;
}

// -------------------- final FC: out = [x0|x1|x2] @ fcW + fcb  (384 -> 40)
// v8: 3-deep LDS pipeline (prefetch 2 chunks ahead). v7 showed the wall is
// load-latency serialization: 1-deep prefetch gives ~700 cyc of hiding vs
// ~1-2k cyc queued load round-trip, so every chunk stalls. With 3 buffers,
// loads for ch+1 and ch+2 stay in flight across barriers (compiler tracks
// per-register vmcnt -> counted waits). Fully unrolled so all xr/xs indices
// are compile-time constants (no scratch). Buffer-reuse safety: S(ch)
// rewrites buf ch%3; its last readers C(ch-3) are sequenced before barrier
// B(ch-1) on every wave in the block.
// W stays scalarized (readfirstlane -> s_load, constant cache).
// xs stride 33: (33*lane + k) % 32 == (lane + k) % 32 -> conflict-free b32.
__global__ __launch_bounds__(256) void final_gemm8(
    const float* __restrict__ X0, const float* __restrict__ X1,
    const float* __restrict__ X2, const float* __restrict__ fcW,
    const float* __restrict__ fcb, float* __restrict__ out) {
    __shared__ float xs[3][64 * 33];    // 3 x 8448 B = 25.3 KB

    const int t = threadIdx.x;
    const int lane = t & 63;
    const int wq = __builtin_amdgcn_readfirstlane(t >> 6);  // col group, SGPR
    const float* wbase = fcW + wq * 10;                     // uniform pointer
    const int rbase = blockIdx.x * 64;

    float acc[10];
    #pragma unroll
    for (int c = 0; c < 10; ++c) acc[c] = 0.0f;

    const float* segs[3] = {X0, X1, X2};
    float4 xr[3][2];                    // 3 in-flight register sets

    // stage 64 rows x 32 k = 8 KB: thread f -> row f>>3, float4 #(f&7).
    // consecutive threads sweep a row's 128 B -> fully coalesced.
    auto load_chunk = [&](int ch, int slot) {
        const float* xseg = segs[ch >> 2];
        const int koff = (ch & 3) * 32;
        #pragma unroll
        for (int i = 0; i < 2; ++i) {
            int f = t + i * 256;
            int row = f >> 3, cc = f & 7;
            int r = rbase + row;
            float4 v = {0, 0, 0, 0};
            if (r < N_NODES)
                v = *(const float4*)(xseg + (size_t)r * 128 + koff + cc * 4);
            xr[slot][i] = v;
        }
    };

    auto store_chunk = [&](int slot) {
        #pragma unroll
        for (int i = 0; i < 2; ++i) {
            int f = t + i * 256;
            int row = f >> 3, cc = f & 7;
            float* p = &xs[slot][row * 33 + cc * 4];
            p[0] = xr[slot][i].x; p[1] = xr[slot][i].y;
            p[2] = xr[slot][i].z; p[3] = xr[slot][i].w;
        }
    };

    load_chunk(0, 0);
    load_chunk(1, 1);
    #pragma unroll
    for (int ch = 0; ch < 12; ++ch) {
        const int slot = ch % 3;
        store_chunk(slot);                          // waits only ch's loads
        if (ch + 2 < 12) load_chunk(ch + 2, (ch + 2) % 3);  // 2-ahead
        __syncthreads();
        const int k0 = ch * 32;
        #pragma unroll
        for (int kk4 = 0; kk4 < 8; ++kk4) {
            float xv[4];
            #pragma unroll
            for (int j = 0; j < 4; ++j)
                xv[j] = xs[slot][lane * 33 + kk4 * 4 + j];
            #pragma unroll
            for (int j = 0; j < 4; ++j) {
                const float* wr = wbase + (size_t)(k0 + kk4 * 4 + j) * 40;
                #pragma unroll
                for (int c = 0; c < 10; ++c)
                    acc[c] = fmaf(xv[j], wr[c], acc[c]);   // s_load'd W
            }
        }
        // no trailing sync: S(ch+1) writes buf (ch+1)%3, whose readers
        // C(ch-2) completed before B(ch) on all waves.
    }

    const int r = rbase + lane;
    if (r < N_NODES) {
        #pragma unroll
        for (int c2 = 0; c2 < 5; ++c2) {
            float2 o;
            o.x = acc[c2 * 2 + 0] + fcb[wq * 10 + c2 * 2 + 0];
            o.y = acc[c2 * 2 + 1] + fcb[wq * 10 + c2 * 2 + 1];
            *(float2*)(out + (size_t)r * 40 + wq * 10 + c2 * 2) = o;
        }
    }
}

// ---------------------------------------------------------------------------
extern "C" void kernel_launch(void* const* d_in, const int* in_sizes, int n_in,
                              void* d_out, int out_size, void* d_ws, size_t ws_size,
                              hipStream_t stream) {
    const float* x   = (const float*)d_in[0];
    const int*   ei  = (const int*)d_in[1];
    const int* e_row = ei;
    const int* e_col = ei + N_EDGES;
    const float* W1  = (const float*)d_in[2];
    const float* b1  = (const float*)d_in[3];
    const float* W2  = (const float*)d_in[4];
    const float* b2  = (const float*)d_in[5];
    const float* g1  = (const float*)d_in[6];
    const float* be1 = (const float*)d_in[7];
    const float* m1  = (const float*)d_in[8];
    const float* v1  = (const float*)d_in[9];
    const float* g2  = (const float*)d_in[10];
    const float* be2 = (const float*)d_in[11];
    const float* m2  = (const float*)d_in[12];
    const float* v2  = (const float*)d_in[13];
    const float* fcW = (const float*)d_in[14];
    const float* fcb = (const float*)d_in[15];
    float* out = (float*)d_out;

    char* ws = (char*)d_ws;
    size_t off = 0;
    auto alloc = [&](size_t b) {
        char* p = ws + off;
        off += (b + 255) & ~(size_t)255;
        return p;
    };
    uint*  h      = (uint*)alloc((size_t)N_NODES * C_H * 2);     // bf16 Hs
    float* x1     = (float*)alloc((size_t)N_NODES * C_H * 4);
    float* x2     = (float*)alloc((size_t)N_NODES * C_H * 4);
    int2*  pairs  = (int2*)alloc((size_t)N_EDGES * 8);
    int*   cols   = (int*)alloc((size_t)N_EDGES * 4);
    float* dinv   = (float*)alloc(N_NODES * 4);
    int*   rowptr = (int*)alloc((N_NODES + 1) * 4);
    int*   bcnt   = (int*)alloc((NB + 1) * 4);
    int*   bstart = (int*)alloc((NB + 1) * 4);
    int*   bfill  = (int*)alloc((NB + 1) * 4);
    float* coef   = (float*)alloc(512 * 4);
    float* s1 = coef, *t1 = coef + 128, *s2 = coef + 256, *t2 = coef + 384;

    const int nwg_bin = (N_EDGES + CHUNK - 1) / CHUNK;   // 261

    zero_i32<<<2, 256, 0, stream>>>(bcnt, NB);
    bucket_count<<<nwg_bin, 256, 0, stream>>>(e_row, bcnt);
    scan_buckets<<<1, 256, 0, stream>>>(bcnt, bstart, bfill);
    bucket_bin<<<nwg_bin, 256, 0, stream>>>(e_row, e_col, bfill, pairs);
    bucket_csr<<<NB, 256, 0, stream>>>(pairs, bstart, rowptr, dinv, cols);
    bn_coef<<<1, 128, 0, stream>>>(b1, g1, be1, m1, v1, b2, g2, be2, m2, v2,
                                   s1, t1, s2, t2);

    gemm_scaled<<<N_NODES / 32, 256, 0, stream>>>(x, W1, dinv, h);
    spmm_bn_relu4<<<N_NODES / 4, 256, 0, stream>>>(h, cols, rowptr, dinv, s1, t1, x1);
    gemm_scaled<<<N_NODES / 32, 256, 0, stream>>>(x1, W2, dinv, h);
    spmm_bn_relu4<<<N_NODES / 4, 256, 0, stream>>>(h, cols, rowptr, dinv, s2, t2, x2);
    final_gemm8<<<(N_NODES + 63) / 64, 256, 0, stream>>>(x, x1, x2, fcW, fcb, out);
}

// Round 3
// 878.141 us; speedup vs baseline: 1.2939x; 1.2939x over previous
//
#include <hip/hip_runtime.h>

#define N_NODES 100000
#define N_EDGES 1600000
#define C_H     128
#define C_OUT   40
#define K_FC    384
#define BN_EPS  1e-5f
#define NB      391        // buckets: row >> 8
#define CHUNK   6144       // edges per binning workgroup

typedef unsigned int uint;

// ---------------------------------------------------------------- utilities
__global__ void zero_i32(int* p, int n) {
    int i = blockIdx.x * blockDim.x + threadIdx.x;
    if (i < n) p[i] = 0;
}

// -------- CSR build, stage 1: per-chunk LDS histogram over 391 buckets
__global__ __launch_bounds__(256) void bucket_count(const int* __restrict__ erow,
                                                    int* __restrict__ bcnt) {
    __shared__ int cnt[NB];
    for (int i = threadIdx.x; i < NB; i += 256) cnt[i] = 0;
    __syncthreads();
    const int c0 = blockIdx.x * CHUNK;
    const int c1 = min(c0 + CHUNK, N_EDGES);
    for (int e = c0 + threadIdx.x; e < c1; e += 256)
        atomicAdd(&cnt[erow[e] >> 8], 1);
    __syncthreads();
    for (int i = threadIdx.x; i < NB; i += 256)
        if (cnt[i]) atomicAdd(&bcnt[i], cnt[i]);
}

// -------- stage 2: exclusive scan of bucket counts (single WG)
__global__ __launch_bounds__(256) void scan_buckets(const int* __restrict__ bcnt,
                                                    int* __restrict__ bstart,
                                                    int* __restrict__ bfill) {
    __shared__ int sa[512], sb[512];
    const int t = threadIdx.x;
    int v0 = (t < NB) ? bcnt[t] : 0;
    int v1 = (t + 256 < NB) ? bcnt[t + 256] : 0;
    sa[t] = v0; sa[t + 256] = v1;
    __syncthreads();
    int* src = sa; int* dst = sb;
    for (int off = 1; off < 512; off <<= 1) {
        dst[t]       = src[t]       + (t >= off ? src[t - off] : 0);
        dst[t + 256] = src[t + 256] + (t + 256 >= off ? src[t + 256 - off] : 0);
        __syncthreads();
        int* tmp = src; src = dst; dst = tmp;
    }
    if (t < NB)       { bstart[t] = src[t] - v0;             bfill[t] = src[t] - v0; }
    if (t + 256 < NB) { bstart[t + 256] = src[t + 256] - v1; bfill[t + 256] = src[t + 256] - v1; }
    if (t == 0) bstart[NB] = N_EDGES;
}

// -------- stage 3: scatter (row,col) pairs into per-bucket dense ranges
__global__ __launch_bounds__(256) void bucket_bin(const int* __restrict__ erow,
                                                  const int* __restrict__ ecol,
                                                  int* __restrict__ bfill,
                                                  int2* __restrict__ pairs) {
    __shared__ int cnt[NB];
    __shared__ int lpos[NB];
    for (int i = threadIdx.x; i < NB; i += 256) cnt[i] = 0;
    __syncthreads();
    const int c0 = blockIdx.x * CHUNK;
    const int c1 = min(c0 + CHUNK, N_EDGES);
    for (int e = c0 + threadIdx.x; e < c1; e += 256)
        atomicAdd(&cnt[erow[e] >> 8], 1);
    __syncthreads();
    for (int i = threadIdx.x; i < NB; i += 256)
        lpos[i] = cnt[i] ? atomicAdd(&bfill[i], cnt[i]) : 0;
    __syncthreads();
    for (int e = c0 + threadIdx.x; e < c1; e += 256) {
        int r = erow[e], c = ecol[e];
        int p = atomicAdd(&lpos[r >> 8], 1);
        pairs[p] = make_int2(r, c);
    }
}

// -------- stage 4: per-bucket local sort -> rowptr, dinv, cols (one WG/bucket)
__global__ __launch_bounds__(256) void bucket_csr(const int2* __restrict__ pairs,
                                                  const int* __restrict__ bstart,
                                                  int* __restrict__ rowptr,
                                                  float* __restrict__ dinv,
                                                  int* __restrict__ colsg) {
    __shared__ int lcnt[256], sa[256], sb[256], lpos[256];
    const int b = blockIdx.x;
    const int t = threadIdx.x;
    const int p0 = bstart[b], p1 = bstart[b + 1];
    lcnt[t] = 0;
    __syncthreads();
    for (int i = p0 + t; i < p1; i += 256)
        atomicAdd(&lcnt[pairs[i].x & 255], 1);
    __syncthreads();
    sa[t] = lcnt[t];
    __syncthreads();
    int* src = sa; int* dst = sb;
    for (int off = 1; off < 256; off <<= 1) {
        dst[t] = src[t] + (t >= off ? src[t - off] : 0);
        __syncthreads();
        int* tmp = src; src = dst; dst = tmp;
    }
    const int excl = src[t] - lcnt[t];
    const int r = b * 256 + t;
    if (r < N_NODES) {
        rowptr[r] = p0 + excl;
        dinv[r] = rsqrtf((float)lcnt[t] + 1.0f);
    }
    if (b == NB - 1 && t == 0) rowptr[N_NODES] = N_EDGES;
    lpos[t] = excl;
    __syncthreads();
    for (int i = p0 + t; i < p1; i += 256) {
        int2 pr = pairs[i];
        int s = atomicAdd(&lpos[pr.x & 255], 1);
        colsg[p0 + s] = pr.y;
    }
}

// relu(bn(agg + b)) = relu(agg*s + t)
__global__ void bn_coef(const float* b1, const float* g1, const float* be1,
                        const float* m1, const float* v1,
                        const float* b2, const float* g2, const float* be2,
                        const float* m2, const float* v2,
                        float* s1, float* t1, float* s2, float* t2) {
    int f = threadIdx.x;
    float sa = g1[f] * rsqrtf(v1[f] + BN_EPS);
    s1[f] = sa;
    t1[f] = (b1[f] - m1[f]) * sa + be1[f];
    float sb = g2[f] * rsqrtf(v2[f] + BN_EPS);
    s2[f] = sb;
    t2[f] = (b2[f] - m2[f]) * sb + be2[f];
}

#define FMA4(A, S, V) \
    A.x = fmaf(S, V.x, A.x); A.y = fmaf(S, V.y, A.y); \
    A.z = fmaf(S, V.z, A.z); A.w = fmaf(S, V.w, A.w);

__device__ inline uint pack_bf16x2(float a, float b) {
    uint ua = __builtin_bit_cast(uint, a);
    uint ub = __builtin_bit_cast(uint, b);
    ua += 0x7fffu + ((ua >> 16) & 1u);   // RNE
    ub += 0x7fffu + ((ub >> 16) & 1u);
    return (ua >> 16) | (ub & 0xffff0000u);
}

// -------------------- GEMM + dinv prescale: Hs(bf16) = diag(dinv) * (X @ W)
__global__ __launch_bounds__(256) void gemm_scaled(const float* __restrict__ X,
                                                   const float* __restrict__ W,
                                                   const float* __restrict__ dinv,
                                                   uint* __restrict__ Hs) {
    __shared__ float wl[64 * 128];   // k-half of W  (32 KB)
    __shared__ float xl[32 * 68];    // 32 rows x 64 cols, stride 68

    const int tid = threadIdx.x;
    const int rg = tid >> 5;
    const int c4 = (tid & 31) << 2;
    const int rb = blockIdx.x * 32;
    const int r0 = rb + rg * 4;

    float4 acc0 = {0,0,0,0}, acc1 = {0,0,0,0}, acc2 = {0,0,0,0}, acc3 = {0,0,0,0};

    for (int half = 0; half < 2; ++half) {
        const int k0 = half * 64;
        __syncthreads();
        {
            const float4* W4 = (const float4*)(W + (size_t)k0 * 128);
            float4* wl4 = (float4*)wl;
            #pragma unroll
            for (int i = 0; i < 8; ++i) wl4[tid + i * 256] = W4[tid + i * 256];
        }
        #pragma unroll
        for (int i = 0; i < 2; ++i) {
            int f = tid + i * 256;
            int row = f >> 4, cc = f & 15;
            float4 v = *(const float4*)(X + (size_t)(rb + row) * 128 + k0 + cc * 4);
            *(float4*)&xl[row * 68 + cc * 4] = v;
        }
        __syncthreads();

        for (int k4 = 0; k4 < 16; ++k4) {
            const float* wr = wl + k4 * 4 * 128 + c4;
            float4 w0 = *(const float4*)(wr);
            float4 w1 = *(const float4*)(wr + 128);
            float4 w2 = *(const float4*)(wr + 256);
            float4 w3 = *(const float4*)(wr + 384);
            float4 xv0 = *(const float4*)&xl[(rg * 4 + 0) * 68 + k4 * 4];
            float4 xv1 = *(const float4*)&xl[(rg * 4 + 1) * 68 + k4 * 4];
            float4 xv2 = *(const float4*)&xl[(rg * 4 + 2) * 68 + k4 * 4];
            float4 xv3 = *(const float4*)&xl[(rg * 4 + 3) * 68 + k4 * 4];
            FMA4(acc0, xv0.x, w0) FMA4(acc0, xv0.y, w1) FMA4(acc0, xv0.z, w2) FMA4(acc0, xv0.w, w3)
            FMA4(acc1, xv1.x, w0) FMA4(acc1, xv1.y, w1) FMA4(acc1, xv1.z, w2) FMA4(acc1, xv1.w, w3)
            FMA4(acc2, xv2.x, w0) FMA4(acc2, xv2.y, w1) FMA4(acc2, xv2.z, w2) FMA4(acc2, xv2.w, w3)
            FMA4(acc3, xv3.x, w0) FMA4(acc3, xv3.y, w1) FMA4(acc3, xv3.z, w2) FMA4(acc3, xv3.w, w3)
        }
    }
    float d0 = dinv[r0], d1 = dinv[r0 + 1], d2 = dinv[r0 + 2], d3 = dinv[r0 + 3];
    uint2 o;
    o.x = pack_bf16x2(acc0.x * d0, acc0.y * d0);
    o.y = pack_bf16x2(acc0.z * d0, acc0.w * d0);
    *(uint2*)(Hs + (size_t)(r0 + 0) * 64 + (c4 >> 1)) = o;
    o.x = pack_bf16x2(acc1.x * d1, acc1.y * d1);
    o.y = pack_bf16x2(acc1.z * d1, acc1.w * d1);
    *(uint2*)(Hs + (size_t)(r0 + 1) * 64 + (c4 >> 1)) = o;
    o.x = pack_bf16x2(acc2.x * d2, acc2.y * d2);
    o.y = pack_bf16x2(acc2.z * d2, acc2.w * d2);
    *(uint2*)(Hs + (size_t)(r0 + 2) * 64 + (c4 >> 1)) = o;
    o.x = pack_bf16x2(acc3.x * d3, acc3.y * d3);
    o.y = pack_bf16x2(acc3.z * d3, acc3.w * d3);
    *(uint2*)(Hs + (size_t)(r0 + 3) * 64 + (c4 >> 1)) = o;
}

// -------------------- SpMM on prescaled bf16 Hs: one wave per row, 2ch/lane.
// 16-deep gather pipeline, then 4, then 1.
#define ACC1(V) \
    accx += __builtin_bit_cast(float, V << 16); \
    accy += __builtin_bit_cast(float, V & 0xffff0000u);

__global__ __launch_bounds__(256) void spmm_bn_relu4(
    const uint* __restrict__ Hs, const int* __restrict__ cols,
    const int* __restrict__ rowptr, const float* __restrict__ dinv,
    const float* __restrict__ s, const float* __restrict__ t,
    float* __restrict__ Y) {
    const int lane = threadIdx.x & 63;
    const int r = blockIdx.x * 4 + (threadIdx.x >> 6);

    uint vself = Hs[(size_t)r * 64 + lane];
    float accx = __builtin_bit_cast(float, vself << 16);
    float accy = __builtin_bit_cast(float, vself & 0xffff0000u);
    const float di = dinv[r];
    const int e0 = rowptr[r], e1 = rowptr[r + 1];
    int j = e0;
    const int n16 = e0 + ((e1 - e0) & ~15);
    for (; j < n16; j += 16) {
        uint v[16];
        #pragma unroll
        for (int q = 0; q < 16; ++q)
            v[q] = Hs[(size_t)cols[j + q] * 64 + lane];
        #pragma unroll
        for (int q = 0; q < 16; ++q) { ACC1(v[q]) }
    }
    const int n4 = e0 + ((e1 - e0) & ~3);
    for (; j < n4; j += 4) {
        uint v[4];
        #pragma unroll
        for (int q = 0; q < 4; ++q)
            v[q] = Hs[(size_t)cols[j + q] * 64 + lane];
        #pragma unroll
        for (int q = 0; q < 4; ++q) { ACC1(v[q]) }
    }
    for (; j < e1; ++j) {
        uint v0 = Hs[(size_t)cols[j] * 64 + lane];
        ACC1(v0)
    }
    float2 sf = ((const float2*)s)[lane];
    float2 tf = ((const float2*)t)[lane];
    float2 o;
    o.x = fmaxf(fmaf(accx * di, sf.x, tf.x), 0.0f);
    o.y = fmaxf(fmaf(accy * di, sf.y, tf.y), 0.0f);
    ((float2*)Y)[(size_t)r * 64 + lane] = o;
}

// -------------------- final FC: out = [x0|x1|x2] @ fcW + fcb  (384 -> 40)
// v9: cross-barrier prefetch via RAW s_barrier. Diagnosis from v6/v7/v8:
// __syncthreads() makes hipcc emit `s_waitcnt vmcnt(0)` before s_barrier,
// draining every in-flight global load -> all source-level prefetch was
// nullified (v6==v7==101us, VALUBusy 22% = pure-FMA cycle fraction).
// Here: own LDS writes flushed with an explicit `s_waitcnt lgkmcnt(0)`,
// then a raw s_barrier (NO vmcnt drain) -> loads for chunks ch+1/ch+2 stay
// in flight across barriers; the consuming ds_write gets a compiler-counted
// vmcnt(N) wait. sched_barrier(0) fences stop the scheduler from moving
// LDS ops across the barrier (guide rule #18).
// Register discipline (v8 lesson, rule #20): TWO named float4 sets A/B
// (ping-pong over even/odd chunks) -> no register arrays, no scratch, and
// WAR on A/B structurally caps in-flight load sets at 2 (VGPR stays low).
// 3 LDS slots (runtime byte offsets are fine): slot s rewritten at ch+3,
// last reader finished >=2 barriers earlier.
// xs stride 33: bank = (lane + k) % 32 -> worst 2-way aliasing (free).
__global__ __launch_bounds__(256) void final_gemm9(
    const float* __restrict__ X0, const float* __restrict__ X1,
    const float* __restrict__ X2, const float* __restrict__ fcW,
    const float* __restrict__ fcb, float* __restrict__ out) {
    __shared__ float xs[3 * 64 * 33];   // 3 slots x 8448 B = 25.3 KB

    const int t = threadIdx.x;
    const int lane = t & 63;
    const int wq = __builtin_amdgcn_readfirstlane(t >> 6);  // col group, SGPR
    const float* wbase = fcW + wq * 10;                     // uniform pointer
    const int rbase = blockIdx.x * 64;

    float acc[10];
    #pragma unroll
    for (int c = 0; c < 10; ++c) acc[c] = 0.0f;

    float4 A0, A1, B0, B1;   // two named in-flight register sets

// issue chunk CH's loads into register pair (R0,R1); 64 rows x 32 k = 8 KB,
// thread f -> row f>>3, float4 #(f&7): consecutive threads sweep a row's
// 128 B -> fully coalesced.
#define LOADC(CH, R0, R1) do {                                               \
    const float* xseg = ((CH) < 4) ? X0 : ((CH) < 8) ? X1 : X2;              \
    const int koff_ = ((CH) & 3) * 32;                                       \
    {   int f_ = t;       int row_ = f_ >> 3, cc_ = f_ & 7;                  \
        int r_ = rbase + row_;                                               \
        float4 v_ = {0, 0, 0, 0};                                            \
        if (r_ < N_NODES)                                                    \
            v_ = *(const float4*)(xseg + (size_t)r_ * 128 + koff_ + cc_ * 4);\
        R0 = v_; }                                                           \
    {   int f_ = t + 256; int row_ = f_ >> 3, cc_ = f_ & 7;                  \
        int r_ = rbase + row_;                                               \
        float4 v_ = {0, 0, 0, 0};                                            \
        if (r_ < N_NODES)                                                    \
            v_ = *(const float4*)(xseg + (size_t)r_ * 128 + koff_ + cc_ * 4);\
        R1 = v_; }                                                           \
} while (0)

// ds_write register pair into LDS slot (compiler inserts counted vmcnt
// for exactly these registers' loads; younger loads stay in flight)
#define STOREC(SLOT, R0, R1) do {                                            \
    float* base_ = xs + (SLOT) * 2112;                                       \
    {   int f_ = t;       float* p_ = base_ + (f_ >> 3) * 33 + (f_ & 7) * 4; \
        p_[0] = R0.x; p_[1] = R0.y; p_[2] = R0.z; p_[3] = R0.w; }            \
    {   int f_ = t + 256; float* p_ = base_ + (f_ >> 3) * 33 + (f_ & 7) * 4; \
        p_[0] = R1.x; p_[1] = R1.y; p_[2] = R1.z; p_[3] = R1.w; }            \
} while (0)

// drain-free barrier: own LDS writes visible, global loads untouched
#define SYNC() do {                                                          \
    asm volatile("s_waitcnt lgkmcnt(0)" ::: "memory");                       \
    __builtin_amdgcn_sched_barrier(0);                                       \
    __builtin_amdgcn_s_barrier();                                            \
    __builtin_amdgcn_sched_barrier(0);                                       \
} while (0)

#define COMPUTEC(CH, SLOT) do {                                              \
    const float* base_ = xs + (SLOT) * 2112 + lane * 33;                     \
    const int k0_ = (CH) * 32;                                               \
    _Pragma("unroll")                                                        \
    for (int kk4 = 0; kk4 < 8; ++kk4) {                                      \
        float xv_[4];                                                        \
        _Pragma("unroll")                                                    \
        for (int j = 0; j < 4; ++j) xv_[j] = base_[kk4 * 4 + j];             \
        _Pragma("unroll")                                                    \
        for (int j = 0; j < 4; ++j) {                                        \
            const float* wr_ = wbase + (size_t)(k0_ + kk4 * 4 + j) * 40;     \
            _Pragma("unroll")                                                \
            for (int c = 0; c < 10; ++c)                                     \
                acc[c] = fmaf(xv_[j], wr_[c], acc[c]);   /* s_load'd W */    \
        }                                                                    \
    }                                                                        \
} while (0)

    LOADC(0, A0, A1);
    LOADC(1, B0, B1);
    #pragma unroll
    for (int p = 0; p < 6; ++p) {
        const int ce = 2 * p, co = 2 * p + 1;
        const int se = ce % 3, so = co % 3;
        STOREC(se, A0, A1);                       // waits ce's loads only
        if (ce + 2 < 12) LOADC(ce + 2, A0, A1);   // 2-ahead, stays in flight
        SYNC();
        COMPUTEC(ce, se);
        STOREC(so, B0, B1);                       // waits co's loads only
        if (co + 2 < 12) LOADC(co + 2, B0, B1);
        SYNC();
        COMPUTEC(co, so);
    }

#undef LOADC
#undef STOREC
#undef SYNC
#undef COMPUTEC

    const int r = rbase + lane;
    if (r < N_NODES) {
        #pragma unroll
        for (int c2 = 0; c2 < 5; ++c2) {
            float2 o;
            o.x = acc[c2 * 2 + 0] + fcb[wq * 10 + c2 * 2 + 0];
            o.y = acc[c2 * 2 + 1] + fcb[wq * 10 + c2 * 2 + 1];
            *(float2*)(out + (size_t)r * 40 + wq * 10 + c2 * 2) = o;
        }
    }
}

// ---------------------------------------------------------------------------
extern "C" void kernel_launch(void* const* d_in, const int* in_sizes, int n_in,
                              void* d_out, int out_size, void* d_ws, size_t ws_size,
                              hipStream_t stream) {
    const float* x   = (const float*)d_in[0];
    const int*   ei  = (const int*)d_in[1];
    const int* e_row = ei;
    const int* e_col = ei + N_EDGES;
    const float* W1  = (const float*)d_in[2];
    const float* b1  = (const float*)d_in[3];
    const float* W2  = (const float*)d_in[4];
    const float* b2  = (const float*)d_in[5];
    const float* g1  = (const float*)d_in[6];
    const float* be1 = (const float*)d_in[7];
    const float* m1  = (const float*)d_in[8];
    const float* v1  = (const float*)d_in[9];
    const float* g2  = (const float*)d_in[10];
    const float* be2 = (const float*)d_in[11];
    const float* m2  = (const float*)d_in[12];
    const float* v2  = (const float*)d_in[13];
    const float* fcW = (const float*)d_in[14];
    const float* fcb = (const float*)d_in[15];
    float* out = (float*)d_out;

    char* ws = (char*)d_ws;
    size_t off = 0;
    auto alloc = [&](size_t b) {
        char* p = ws + off;
        off += (b + 255) & ~(size_t)255;
        return p;
    };
    uint*  h      = (uint*)alloc((size_t)N_NODES * C_H * 2);     // bf16 Hs
    float* x1     = (float*)alloc((size_t)N_NODES * C_H * 4);
    float* x2     = (float*)alloc((size_t)N_NODES * C_H * 4);
    int2*  pairs  = (int2*)alloc((size_t)N_EDGES * 8);
    int*   cols   = (int*)alloc((size_t)N_EDGES * 4);
    float* dinv   = (float*)alloc(N_NODES * 4);
    int*   rowptr = (int*)alloc((N_NODES + 1) * 4);
    int*   bcnt   = (int*)alloc((NB + 1) * 4);
    int*   bstart = (int*)alloc((NB + 1) * 4);
    int*   bfill  = (int*)alloc((NB + 1) * 4);
    float* coef   = (float*)alloc(512 * 4);
    float* s1 = coef, *t1 = coef + 128, *s2 = coef + 256, *t2 = coef + 384;

    const int nwg_bin = (N_EDGES + CHUNK - 1) / CHUNK;   // 261

    zero_i32<<<2, 256, 0, stream>>>(bcnt, NB);
    bucket_count<<<nwg_bin, 256, 0, stream>>>(e_row, bcnt);
    scan_buckets<<<1, 256, 0, stream>>>(bcnt, bstart, bfill);
    bucket_bin<<<nwg_bin, 256, 0, stream>>>(e_row, e_col, bfill, pairs);
    bucket_csr<<<NB, 256, 0, stream>>>(pairs, bstart, rowptr, dinv, cols);
    bn_coef<<<1, 128, 0, stream>>>(b1, g1, be1, m1, v1, b2, g2, be2, m2, v2,
                                   s1, t1, s2, t2);

    gemm_scaled<<<N_NODES / 32, 256, 0, stream>>>(x, W1, dinv, h);
    spmm_bn_relu4<<<N_NODES / 4, 256, 0, stream>>>(h, cols, rowptr, dinv, s1, t1, x1);
    gemm_scaled<<<N_NODES / 32, 256, 0, stream>>>(x1, W2, dinv, h);
    spmm_bn_relu4<<<N_NODES / 4, 256, 0, stream>>>(h, cols, rowptr, dinv, s2, t2, x2);
    final_gemm9<<<(N_NODES + 63) / 64, 256, 0, stream>>>(x, x1, x2, fcW, fcb, out);
}

// Round 4
// 518.947 us; speedup vs baseline: 2.1895x; 1.6922x over previous
//
#include <hip/hip_runtime.h>

#define N_NODES 100000
#define N_EDGES 1600000
#define C_H     128
#define C_OUT   40
#define K_FC    384
#define BN_EPS  1e-5f
#define NB      391        // buckets: row >> 8
#define CHUNK   6144       // edges per binning workgroup

typedef unsigned int uint;

// ---------------------------------------------------------------- utilities
__global__ void zero_i32(int* p, int n) {
    int i = blockIdx.x * blockDim.x + threadIdx.x;
    if (i < n) p[i] = 0;
}

// -------- CSR build, stage 1: per-chunk LDS histogram over 391 buckets
__global__ __launch_bounds__(256) void bucket_count(const int* __restrict__ erow,
                                                    int* __restrict__ bcnt) {
    __shared__ int cnt[NB];
    for (int i = threadIdx.x; i < NB; i += 256) cnt[i] = 0;
    __syncthreads();
    const int c0 = blockIdx.x * CHUNK;
    const int c1 = min(c0 + CHUNK, N_EDGES);
    for (int e = c0 + threadIdx.x; e < c1; e += 256)
        atomicAdd(&cnt[erow[e] >> 8], 1);
    __syncthreads();
    for (int i = threadIdx.x; i < NB; i += 256)
        if (cnt[i]) atomicAdd(&bcnt[i], cnt[i]);
}

// -------- stage 2: exclusive scan of bucket counts (single WG)
__global__ __launch_bounds__(256) void scan_buckets(const int* __restrict__ bcnt,
                                                    int* __restrict__ bstart,
                                                    int* __restrict__ bfill) {
    __shared__ int sa[512], sb[512];
    const int t = threadIdx.x;
    int v0 = (t < NB) ? bcnt[t] : 0;
    int v1 = (t + 256 < NB) ? bcnt[t + 256] : 0;
    sa[t] = v0; sa[t + 256] = v1;
    __syncthreads();
    int* src = sa; int* dst = sb;
    for (int off = 1; off < 512; off <<= 1) {
        dst[t]       = src[t]       + (t >= off ? src[t - off] : 0);
        dst[t + 256] = src[t + 256] + (t + 256 >= off ? src[t + 256 - off] : 0);
        __syncthreads();
        int* tmp = src; src = dst; dst = tmp;
    }
    if (t < NB)       { bstart[t] = src[t] - v0;             bfill[t] = src[t] - v0; }
    if (t + 256 < NB) { bstart[t + 256] = src[t + 256] - v1; bfill[t + 256] = src[t + 256] - v1; }
    if (t == 0) bstart[NB] = N_EDGES;
}

// -------- stage 3: scatter (row,col) pairs into per-bucket dense ranges
__global__ __launch_bounds__(256) void bucket_bin(const int* __restrict__ erow,
                                                  const int* __restrict__ ecol,
                                                  int* __restrict__ bfill,
                                                  int2* __restrict__ pairs) {
    __shared__ int cnt[NB];
    __shared__ int lpos[NB];
    for (int i = threadIdx.x; i < NB; i += 256) cnt[i] = 0;
    __syncthreads();
    const int c0 = blockIdx.x * CHUNK;
    const int c1 = min(c0 + CHUNK, N_EDGES);
    for (int e = c0 + threadIdx.x; e < c1; e += 256)
        atomicAdd(&cnt[erow[e] >> 8], 1);
    __syncthreads();
    for (int i = threadIdx.x; i < NB; i += 256)
        lpos[i] = cnt[i] ? atomicAdd(&bfill[i], cnt[i]) : 0;
    __syncthreads();
    for (int e = c0 + threadIdx.x; e < c1; e += 256) {
        int r = erow[e], c = ecol[e];
        int p = atomicAdd(&lpos[r >> 8], 1);
        pairs[p] = make_int2(r, c);
    }
}

// -------- stage 4: per-bucket local sort -> rowptr, dinv, cols (one WG/bucket)
__global__ __launch_bounds__(256) void bucket_csr(const int2* __restrict__ pairs,
                                                  const int* __restrict__ bstart,
                                                  int* __restrict__ rowptr,
                                                  float* __restrict__ dinv,
                                                  int* __restrict__ colsg) {
    __shared__ int lcnt[256], sa[256], sb[256], lpos[256];
    const int b = blockIdx.x;
    const int t = threadIdx.x;
    const int p0 = bstart[b], p1 = bstart[b + 1];
    lcnt[t] = 0;
    __syncthreads();
    for (int i = p0 + t; i < p1; i += 256)
        atomicAdd(&lcnt[pairs[i].x & 255], 1);
    __syncthreads();
    sa[t] = lcnt[t];
    __syncthreads();
    int* src = sa; int* dst = sb;
    for (int off = 1; off < 256; off <<= 1) {
        dst[t] = src[t] + (t >= off ? src[t - off] : 0);
        __syncthreads();
        int* tmp = src; src = dst; dst = tmp;
    }
    const int excl = src[t] - lcnt[t];
    const int r = b * 256 + t;
    if (r < N_NODES) {
        rowptr[r] = p0 + excl;
        dinv[r] = rsqrtf((float)lcnt[t] + 1.0f);
    }
    if (b == NB - 1 && t == 0) rowptr[N_NODES] = N_EDGES;
    lpos[t] = excl;
    __syncthreads();
    for (int i = p0 + t; i < p1; i += 256) {
        int2 pr = pairs[i];
        int s = atomicAdd(&lpos[pr.x & 255], 1);
        colsg[p0 + s] = pr.y;
    }
}

// relu(bn(agg + b)) = relu(agg*s + t)
__global__ void bn_coef(const float* b1, const float* g1, const float* be1,
                        const float* m1, const float* v1,
                        const float* b2, const float* g2, const float* be2,
                        const float* m2, const float* v2,
                        float* s1, float* t1, float* s2, float* t2) {
    int f = threadIdx.x;
    float sa = g1[f] * rsqrtf(v1[f] + BN_EPS);
    s1[f] = sa;
    t1[f] = (b1[f] - m1[f]) * sa + be1[f];
    float sb = g2[f] * rsqrtf(v2[f] + BN_EPS);
    s2[f] = sb;
    t2[f] = (b2[f] - m2[f]) * sb + be2[f];
}

#define FMA4(A, S, V) \
    A.x = fmaf(S, V.x, A.x); A.y = fmaf(S, V.y, A.y); \
    A.z = fmaf(S, V.z, A.z); A.w = fmaf(S, V.w, A.w);

__device__ inline uint pack_bf16x2(float a, float b) {
    uint ua = __builtin_bit_cast(uint, a);
    uint ub = __builtin_bit_cast(uint, b);
    ua += 0x7fffu + ((ua >> 16) & 1u);   // RNE
    ub += 0x7fffu + ((ub >> 16) & 1u);
    return (ua >> 16) | (ub & 0xffff0000u);
}

// -------------------- GEMM + dinv prescale: Hs(bf16) = diag(dinv) * (X @ W)
__global__ __launch_bounds__(256) void gemm_scaled(const float* __restrict__ X,
                                                   const float* __restrict__ W,
                                                   const float* __restrict__ dinv,
                                                   uint* __restrict__ Hs) {
    __shared__ float wl[64 * 128];   // k-half of W  (32 KB)
    __shared__ float xl[32 * 68];    // 32 rows x 64 cols, stride 68

    const int tid = threadIdx.x;
    const int rg = tid >> 5;
    const int c4 = (tid & 31) << 2;
    const int rb = blockIdx.x * 32;
    const int r0 = rb + rg * 4;

    float4 acc0 = {0,0,0,0}, acc1 = {0,0,0,0}, acc2 = {0,0,0,0}, acc3 = {0,0,0,0};

    for (int half = 0; half < 2; ++half) {
        const int k0 = half * 64;
        __syncthreads();
        {
            const float4* W4 = (const float4*)(W + (size_t)k0 * 128);
            float4* wl4 = (float4*)wl;
            #pragma unroll
            for (int i = 0; i < 8; ++i) wl4[tid + i * 256] = W4[tid + i * 256];
        }
        #pragma unroll
        for (int i = 0; i < 2; ++i) {
            int f = tid + i * 256;
            int row = f >> 4, cc = f & 15;
            float4 v = *(const float4*)(X + (size_t)(rb + row) * 128 + k0 + cc * 4);
            *(float4*)&xl[row * 68 + cc * 4] = v;
        }
        __syncthreads();

        for (int k4 = 0; k4 < 16; ++k4) {
            const float* wr = wl + k4 * 4 * 128 + c4;
            float4 w0 = *(const float4*)(wr);
            float4 w1 = *(const float4*)(wr + 128);
            float4 w2 = *(const float4*)(wr + 256);
            float4 w3 = *(const float4*)(wr + 384);
            float4 xv0 = *(const float4*)&xl[(rg * 4 + 0) * 68 + k4 * 4];
            float4 xv1 = *(const float4*)&xl[(rg * 4 + 1) * 68 + k4 * 4];
            float4 xv2 = *(const float4*)&xl[(rg * 4 + 2) * 68 + k4 * 4];
            float4 xv3 = *(const float4*)&xl[(rg * 4 + 3) * 68 + k4 * 4];
            FMA4(acc0, xv0.x, w0) FMA4(acc0, xv0.y, w1) FMA4(acc0, xv0.z, w2) FMA4(acc0, xv0.w, w3)
            FMA4(acc1, xv1.x, w0) FMA4(acc1, xv1.y, w1) FMA4(acc1, xv1.z, w2) FMA4(acc1, xv1.w, w3)
            FMA4(acc2, xv2.x, w0) FMA4(acc2, xv2.y, w1) FMA4(acc2, xv2.z, w2) FMA4(acc2, xv2.w, w3)
            FMA4(acc3, xv3.x, w0) FMA4(acc3, xv3.y, w1) FMA4(acc3, xv3.z, w2) FMA4(acc3, xv3.w, w3)
        }
    }
    float d0 = dinv[r0], d1 = dinv[r0 + 1], d2 = dinv[r0 + 2], d3 = dinv[r0 + 3];
    uint2 o;
    o.x = pack_bf16x2(acc0.x * d0, acc0.y * d0);
    o.y = pack_bf16x2(acc0.z * d0, acc0.w * d0);
    *(uint2*)(Hs + (size_t)(r0 + 0) * 64 + (c4 >> 1)) = o;
    o.x = pack_bf16x2(acc1.x * d1, acc1.y * d1);
    o.y = pack_bf16x2(acc1.z * d1, acc1.w * d1);
    *(uint2*)(Hs + (size_t)(r0 + 1) * 64 + (c4 >> 1)) = o;
    o.x = pack_bf16x2(acc2.x * d2, acc2.y * d2);
    o.y = pack_bf16x2(acc2.z * d2, acc2.w * d2);
    *(uint2*)(Hs + (size_t)(r0 + 2) * 64 + (c4 >> 1)) = o;
    o.x = pack_bf16x2(acc3.x * d3, acc3.y * d3);
    o.y = pack_bf16x2(acc3.z * d3, acc3.w * d3);
    *(uint2*)(Hs + (size_t)(r0 + 3) * 64 + (c4 >> 1)) = o;
}

// -------------------- SpMM on prescaled bf16 Hs: one wave per row, 2ch/lane.
// 16-deep gather pipeline, then 4, then 1.
#define ACC1(V) \
    accx += __builtin_bit_cast(float, V << 16); \
    accy += __builtin_bit_cast(float, V & 0xffff0000u);

__global__ __launch_bounds__(256) void spmm_bn_relu4(
    const uint* __restrict__ Hs, const int* __restrict__ cols,
    const int* __restrict__ rowptr, const float* __restrict__ dinv,
    const float* __restrict__ s, const float* __restrict__ t,
    float* __restrict__ Y) {
    const int lane = threadIdx.x & 63;
    const int r = blockIdx.x * 4 + (threadIdx.x >> 6);

    uint vself = Hs[(size_t)r * 64 + lane];
    float accx = __builtin_bit_cast(float, vself << 16);
    float accy = __builtin_bit_cast(float, vself & 0xffff0000u);
    const float di = dinv[r];
    const int e0 = rowptr[r], e1 = rowptr[r + 1];
    int j = e0;
    const int n16 = e0 + ((e1 - e0) & ~15);
    for (; j < n16; j += 16) {
        uint v[16];
        #pragma unroll
        for (int q = 0; q < 16; ++q)
            v[q] = Hs[(size_t)cols[j + q] * 64 + lane];
        #pragma unroll
        for (int q = 0; q < 16; ++q) { ACC1(v[q]) }
    }
    const int n4 = e0 + ((e1 - e0) & ~3);
    for (; j < n4; j += 4) {
        uint v[4];
        #pragma unroll
        for (int q = 0; q < 4; ++q)
            v[q] = Hs[(size_t)cols[j + q] * 64 + lane];
        #pragma unroll
        for (int q = 0; q < 4; ++q) { ACC1(v[q]) }
    }
    for (; j < e1; ++j) {
        uint v0 = Hs[(size_t)cols[j] * 64 + lane];
        ACC1(v0)
    }
    float2 sf = ((const float2*)s)[lane];
    float2 tf = ((const float2*)t)[lane];
    float2 o;
    o.x = fmaxf(fmaf(accx * di, sf.x, tf.x), 0.0f);
    o.y = fmaxf(fmaf(accy * di, sf.y, tf.y), 0.0f);
    ((float2*)Y)[(size_t)r * 64 + lane] = o;
}

// -------------------- final FC: out = [x0|x1|x2] @ fcW + fcb  (384 -> 40)
// v10 = v7 with ONE structural change: load_chunk(ch+1) moved to AFTER the
// barrier. v7 issued it before __syncthreads, and hipcc's mandatory
// `s_waitcnt vmcnt(0)` at the barrier drained it instantly -> zero overlap,
// full exposed load latency per chunk (the 101us plateau). Here the barrier
// fires with no vmem outstanding (regs were consumed by store_chunk), then
// loads issue and have the whole compute phase (~640 FMA cycles) to land;
// the NEXT iteration's store waits on them via plain register dependence
// (counted wait, not a drain). v8/v9 lesson: no unroll pragmas, no register
// arrays, no slot rotation -- keep v7's exact low-pressure structure.
// W scalarized via readfirstlane (s_load / constant cache).
// xs stride 33: bank = (lane + k) % 32 -> conflict-free.
__global__ __launch_bounds__(256) void final_gemm10(
    const float* __restrict__ X0, const float* __restrict__ X1,
    const float* __restrict__ X2, const float* __restrict__ fcW,
    const float* __restrict__ fcb, float* __restrict__ out) {
    __shared__ float xs[2][64 * 33];    // 2 x 8448 B

    const int t = threadIdx.x;
    const int lane = t & 63;
    const int wq = __builtin_amdgcn_readfirstlane(t >> 6);  // col group, SGPR
    const float* wbase = fcW + wq * 10;                     // uniform pointer
    const int rbase = blockIdx.x * 64;

    float acc[10];
    #pragma unroll
    for (int c = 0; c < 10; ++c) acc[c] = 0.0f;

    const float* segs[3] = {X0, X1, X2};
    float4 xr[2];

    // stage 64 rows x 32 k = 8 KB: thread f -> row f>>3, float4 #(f&7).
    // consecutive threads sweep a row's 128 B -> fully coalesced.
    auto load_chunk = [&](int ch) {
        const float* xseg = segs[ch >> 2];
        const int koff = (ch & 3) * 32;
        #pragma unroll
        for (int i = 0; i < 2; ++i) {
            int f = t + i * 256;
            int row = f >> 3, cc = f & 7;
            int r = rbase + row;
            float4 v = {0, 0, 0, 0};
            if (r < N_NODES)
                v = *(const float4*)(xseg + (size_t)r * 128 + koff + cc * 4);
            xr[i] = v;
        }
    };

    auto store_chunk = [&](int buf) {
        #pragma unroll
        for (int i = 0; i < 2; ++i) {
            int f = t + i * 256;
            int row = f >> 3, cc = f & 7;
            float* p = &xs[buf][row * 33 + cc * 4];
            p[0] = xr[i].x; p[1] = xr[i].y; p[2] = xr[i].z; p[3] = xr[i].w;
        }
    };

    load_chunk(0);
    for (int ch = 0; ch < 12; ++ch) {
        const int buf = ch & 1;
        store_chunk(buf);            // consumes xr (counted vmcnt wait)
        __syncthreads();             // drain is free: nothing in flight
        if (ch < 11) load_chunk(ch + 1);   // overlaps compute below
        const int k0 = ch * 32;
        #pragma unroll
        for (int kk4 = 0; kk4 < 8; ++kk4) {
            float xv[4];
            #pragma unroll
            for (int j = 0; j < 4; ++j)
                xv[j] = xs[buf][lane * 33 + kk4 * 4 + j];
            #pragma unroll
            for (int j = 0; j < 4; ++j) {
                const float* wr = wbase + (size_t)(k0 + kk4 * 4 + j) * 40;
                #pragma unroll
                for (int c = 0; c < 10; ++c)
                    acc[c] = fmaf(xv[j], wr[c], acc[c]);   // s_load'd W
            }
        }
        // no trailing sync: next iteration writes the OTHER buffer, whose
        // readers (compute of ch-1) all passed this iteration's barrier.
    }

    const int r = rbase + lane;
    if (r < N_NODES) {
        #pragma unroll
        for (int c2 = 0; c2 < 5; ++c2) {
            float2 o;
            o.x = acc[c2 * 2 + 0] + fcb[wq * 10 + c2 * 2 + 0];
            o.y = acc[c2 * 2 + 1] + fcb[wq * 10 + c2 * 2 + 1];
            *(float2*)(out + (size_t)r * 40 + wq * 10 + c2 * 2) = o;
        }
    }
}

// ---------------------------------------------------------------------------
extern "C" void kernel_launch(void* const* d_in, const int* in_sizes, int n_in,
                              void* d_out, int out_size, void* d_ws, size_t ws_size,
                              hipStream_t stream) {
    const float* x   = (const float*)d_in[0];
    const int*   ei  = (const int*)d_in[1];
    const int* e_row = ei;
    const int* e_col = ei + N_EDGES;
    const float* W1  = (const float*)d_in[2];
    const float* b1  = (const float*)d_in[3];
    const float* W2  = (const float*)d_in[4];
    const float* b2  = (const float*)d_in[5];
    const float* g1  = (const float*)d_in[6];
    const float* be1 = (const float*)d_in[7];
    const float* m1  = (const float*)d_in[8];
    const float* v1  = (const float*)d_in[9];
    const float* g2  = (const float*)d_in[10];
    const float* be2 = (const float*)d_in[11];
    const float* m2  = (const float*)d_in[12];
    const float* v2  = (const float*)d_in[13];
    const float* fcW = (const float*)d_in[14];
    const float* fcb = (const float*)d_in[15];
    float* out = (float*)d_out;

    char* ws = (char*)d_ws;
    size_t off = 0;
    auto alloc = [&](size_t b) {
        char* p = ws + off;
        off += (b + 255) & ~(size_t)255;
        return p;
    };
    uint*  h      = (uint*)alloc((size_t)N_NODES * C_H * 2);     // bf16 Hs
    float* x1     = (float*)alloc((size_t)N_NODES * C_H * 4);
    float* x2     = (float*)alloc((size_t)N_NODES * C_H * 4);
    int2*  pairs  = (int2*)alloc((size_t)N_EDGES * 8);
    int*   cols   = (int*)alloc((size_t)N_EDGES * 4);
    float* dinv   = (float*)alloc(N_NODES * 4);
    int*   rowptr = (int*)alloc((N_NODES + 1) * 4);
    int*   bcnt   = (int*)alloc((NB + 1) * 4);
    int*   bstart = (int*)alloc((NB + 1) * 4);
    int*   bfill  = (int*)alloc((NB + 1) * 4);
    float* coef   = (float*)alloc(512 * 4);
    float* s1 = coef, *t1 = coef + 128, *s2 = coef + 256, *t2 = coef + 384;

    const int nwg_bin = (N_EDGES + CHUNK - 1) / CHUNK;   // 261

    zero_i32<<<2, 256, 0, stream>>>(bcnt, NB);
    bucket_count<<<nwg_bin, 256, 0, stream>>>(e_row, bcnt);
    scan_buckets<<<1, 256, 0, stream>>>(bcnt, bstart, bfill);
    bucket_bin<<<nwg_bin, 256, 0, stream>>>(e_row, e_col, bfill, pairs);
    bucket_csr<<<NB, 256, 0, stream>>>(pairs, bstart, rowptr, dinv, cols);
    bn_coef<<<1, 128, 0, stream>>>(b1, g1, be1, m1, v1, b2, g2, be2, m2, v2,
                                   s1, t1, s2, t2);

    gemm_scaled<<<N_NODES / 32, 256, 0, stream>>>(x, W1, dinv, h);
    spmm_bn_relu4<<<N_NODES / 4, 256, 0, stream>>>(h, cols, rowptr, dinv, s1, t1, x1);
    gemm_scaled<<<N_NODES / 32, 256, 0, stream>>>(x1, W2, dinv, h);
    spmm_bn_relu4<<<N_NODES / 4, 256, 0, stream>>>(h, cols, rowptr, dinv, s2, t2, x2);
    final_gemm10<<<(N_NODES + 63) / 64, 256, 0, stream>>>(x, x1, x2, fcW, fcb, out);
}

// Round 5
// 501.873 us; speedup vs baseline: 2.2640x; 1.0340x over previous
//
#include <hip/hip_runtime.h>

#define N_NODES 100000
#define N_EDGES 1600000
#define C_H     128
#define C_OUT   40
#define K_FC    384
#define BN_EPS  1e-5f
#define NB      391        // buckets: row >> 8
#define CHUNK   6144       // edges per binning workgroup

typedef unsigned int uint;

// ---------------------------------------------------------------- utilities
__global__ void zero_i32(int* p, int n) {
    int i = blockIdx.x * blockDim.x + threadIdx.x;
    if (i < n) p[i] = 0;
}

// -------- CSR build, stage 1: per-chunk LDS histogram over 391 buckets
__global__ __launch_bounds__(256) void bucket_count(const int* __restrict__ erow,
                                                    int* __restrict__ bcnt) {
    __shared__ int cnt[NB];
    for (int i = threadIdx.x; i < NB; i += 256) cnt[i] = 0;
    __syncthreads();
    const int c0 = blockIdx.x * CHUNK;
    const int c1 = min(c0 + CHUNK, N_EDGES);
    for (int e = c0 + threadIdx.x; e < c1; e += 256)
        atomicAdd(&cnt[erow[e] >> 8], 1);
    __syncthreads();
    for (int i = threadIdx.x; i < NB; i += 256)
        if (cnt[i]) atomicAdd(&bcnt[i], cnt[i]);
}

// -------- stage 2: exclusive scan of bucket counts (single WG)
__global__ __launch_bounds__(256) void scan_buckets(const int* __restrict__ bcnt,
                                                    int* __restrict__ bstart,
                                                    int* __restrict__ bfill) {
    __shared__ int sa[512], sb[512];
    const int t = threadIdx.x;
    int v0 = (t < NB) ? bcnt[t] : 0;
    int v1 = (t + 256 < NB) ? bcnt[t + 256] : 0;
    sa[t] = v0; sa[t + 256] = v1;
    __syncthreads();
    int* src = sa; int* dst = sb;
    for (int off = 1; off < 512; off <<= 1) {
        dst[t]       = src[t]       + (t >= off ? src[t - off] : 0);
        dst[t + 256] = src[t + 256] + (t + 256 >= off ? src[t + 256 - off] : 0);
        __syncthreads();
        int* tmp = src; src = dst; dst = tmp;
    }
    if (t < NB)       { bstart[t] = src[t] - v0;             bfill[t] = src[t] - v0; }
    if (t + 256 < NB) { bstart[t + 256] = src[t + 256] - v1; bfill[t + 256] = src[t + 256] - v1; }
    if (t == 0) bstart[NB] = N_EDGES;
}

// -------- stage 3: scatter (row,col) pairs into per-bucket dense ranges
__global__ __launch_bounds__(256) void bucket_bin(const int* __restrict__ erow,
                                                  const int* __restrict__ ecol,
                                                  int* __restrict__ bfill,
                                                  int2* __restrict__ pairs) {
    __shared__ int cnt[NB];
    __shared__ int lpos[NB];
    for (int i = threadIdx.x; i < NB; i += 256) cnt[i] = 0;
    __syncthreads();
    const int c0 = blockIdx.x * CHUNK;
    const int c1 = min(c0 + CHUNK, N_EDGES);
    for (int e = c0 + threadIdx.x; e < c1; e += 256)
        atomicAdd(&cnt[erow[e] >> 8], 1);
    __syncthreads();
    for (int i = threadIdx.x; i < NB; i += 256)
        lpos[i] = cnt[i] ? atomicAdd(&bfill[i], cnt[i]) : 0;
    __syncthreads();
    for (int e = c0 + threadIdx.x; e < c1; e += 256) {
        int r = erow[e], c = ecol[e];
        int p = atomicAdd(&lpos[r >> 8], 1);
        pairs[p] = make_int2(r, c);
    }
}

// -------- stage 4: per-bucket local sort -> rowptr, dinv, cols (one WG/bucket)
__global__ __launch_bounds__(256) void bucket_csr(const int2* __restrict__ pairs,
                                                  const int* __restrict__ bstart,
                                                  int* __restrict__ rowptr,
                                                  float* __restrict__ dinv,
                                                  int* __restrict__ colsg) {
    __shared__ int lcnt[256], sa[256], sb[256], lpos[256];
    const int b = blockIdx.x;
    const int t = threadIdx.x;
    const int p0 = bstart[b], p1 = bstart[b + 1];
    lcnt[t] = 0;
    __syncthreads();
    for (int i = p0 + t; i < p1; i += 256)
        atomicAdd(&lcnt[pairs[i].x & 255], 1);
    __syncthreads();
    sa[t] = lcnt[t];
    __syncthreads();
    int* src = sa; int* dst = sb;
    for (int off = 1; off < 256; off <<= 1) {
        dst[t] = src[t] + (t >= off ? src[t - off] : 0);
        __syncthreads();
        int* tmp = src; src = dst; dst = tmp;
    }
    const int excl = src[t] - lcnt[t];
    const int r = b * 256 + t;
    if (r < N_NODES) {
        rowptr[r] = p0 + excl;
        dinv[r] = rsqrtf((float)lcnt[t] + 1.0f);
    }
    if (b == NB - 1 && t == 0) rowptr[N_NODES] = N_EDGES;
    lpos[t] = excl;
    __syncthreads();
    for (int i = p0 + t; i < p1; i += 256) {
        int2 pr = pairs[i];
        int s = atomicAdd(&lpos[pr.x & 255], 1);
        colsg[p0 + s] = pr.y;
    }
}

// relu(bn(agg + b)) = relu(agg*s + t)
__global__ void bn_coef(const float* b1, const float* g1, const float* be1,
                        const float* m1, const float* v1,
                        const float* b2, const float* g2, const float* be2,
                        const float* m2, const float* v2,
                        float* s1, float* t1, float* s2, float* t2) {
    int f = threadIdx.x;
    float sa = g1[f] * rsqrtf(v1[f] + BN_EPS);
    s1[f] = sa;
    t1[f] = (b1[f] - m1[f]) * sa + be1[f];
    float sb = g2[f] * rsqrtf(v2[f] + BN_EPS);
    s2[f] = sb;
    t2[f] = (b2[f] - m2[f]) * sb + be2[f];
}

#define FMA4(A, S, V) \
    A.x = fmaf(S, V.x, A.x); A.y = fmaf(S, V.y, A.y); \
    A.z = fmaf(S, V.z, A.z); A.w = fmaf(S, V.w, A.w);

__device__ inline uint pack_bf16x2(float a, float b) {
    uint ua = __builtin_bit_cast(uint, a);
    uint ub = __builtin_bit_cast(uint, b);
    ua += 0x7fffu + ((ua >> 16) & 1u);   // RNE
    ub += 0x7fffu + ((ub >> 16) & 1u);
    return (ua >> 16) | (ub & 0xffff0000u);
}

// -------------------- GEMM + dinv prescale: Hs(bf16) = diag(dinv) * (X @ W)
__global__ __launch_bounds__(256) void gemm_scaled(const float* __restrict__ X,
                                                   const float* __restrict__ W,
                                                   const float* __restrict__ dinv,
                                                   uint* __restrict__ Hs) {
    __shared__ float wl[64 * 128];   // k-half of W  (32 KB)
    __shared__ float xl[32 * 68];    // 32 rows x 64 cols, stride 68

    const int tid = threadIdx.x;
    const int rg = tid >> 5;
    const int c4 = (tid & 31) << 2;
    const int rb = blockIdx.x * 32;
    const int r0 = rb + rg * 4;

    float4 acc0 = {0,0,0,0}, acc1 = {0,0,0,0}, acc2 = {0,0,0,0}, acc3 = {0,0,0,0};

    for (int half = 0; half < 2; ++half) {
        const int k0 = half * 64;
        __syncthreads();
        {
            const float4* W4 = (const float4*)(W + (size_t)k0 * 128);
            float4* wl4 = (float4*)wl;
            #pragma unroll
            for (int i = 0; i < 8; ++i) wl4[tid + i * 256] = W4[tid + i * 256];
        }
        #pragma unroll
        for (int i = 0; i < 2; ++i) {
            int f = tid + i * 256;
            int row = f >> 4, cc = f & 15;
            float4 v = *(const float4*)(X + (size_t)(rb + row) * 128 + k0 + cc * 4);
            *(float4*)&xl[row * 68 + cc * 4] = v;
        }
        __syncthreads();

        for (int k4 = 0; k4 < 16; ++k4) {
            const float* wr = wl + k4 * 4 * 128 + c4;
            float4 w0 = *(const float4*)(wr);
            float4 w1 = *(const float4*)(wr + 128);
            float4 w2 = *(const float4*)(wr + 256);
            float4 w3 = *(const float4*)(wr + 384);
            float4 xv0 = *(const float4*)&xl[(rg * 4 + 0) * 68 + k4 * 4];
            float4 xv1 = *(const float4*)&xl[(rg * 4 + 1) * 68 + k4 * 4];
            float4 xv2 = *(const float4*)&xl[(rg * 4 + 2) * 68 + k4 * 4];
            float4 xv3 = *(const float4*)&xl[(rg * 4 + 3) * 68 + k4 * 4];
            FMA4(acc0, xv0.x, w0) FMA4(acc0, xv0.y, w1) FMA4(acc0, xv0.z, w2) FMA4(acc0, xv0.w, w3)
            FMA4(acc1, xv1.x, w0) FMA4(acc1, xv1.y, w1) FMA4(acc1, xv1.z, w2) FMA4(acc1, xv1.w, w3)
            FMA4(acc2, xv2.x, w0) FMA4(acc2, xv2.y, w1) FMA4(acc2, xv2.z, w2) FMA4(acc2, xv2.w, w3)
            FMA4(acc3, xv3.x, w0) FMA4(acc3, xv3.y, w1) FMA4(acc3, xv3.z, w2) FMA4(acc3, xv3.w, w3)
        }
    }
    float d0 = dinv[r0], d1 = dinv[r0 + 1], d2 = dinv[r0 + 2], d3 = dinv[r0 + 3];
    uint2 o;
    o.x = pack_bf16x2(acc0.x * d0, acc0.y * d0);
    o.y = pack_bf16x2(acc0.z * d0, acc0.w * d0);
    *(uint2*)(Hs + (size_t)(r0 + 0) * 64 + (c4 >> 1)) = o;
    o.x = pack_bf16x2(acc1.x * d1, acc1.y * d1);
    o.y = pack_bf16x2(acc1.z * d1, acc1.w * d1);
    *(uint2*)(Hs + (size_t)(r0 + 1) * 64 + (c4 >> 1)) = o;
    o.x = pack_bf16x2(acc2.x * d2, acc2.y * d2);
    o.y = pack_bf16x2(acc2.z * d2, acc2.w * d2);
    *(uint2*)(Hs + (size_t)(r0 + 2) * 64 + (c4 >> 1)) = o;
    o.x = pack_bf16x2(acc3.x * d3, acc3.y * d3);
    o.y = pack_bf16x2(acc3.z * d3, acc3.w * d3);
    *(uint2*)(Hs + (size_t)(r0 + 3) * 64 + (c4 >> 1)) = o;
}

// -------------------- SpMM on prescaled bf16 Hs: one wave per row, 2ch/lane.
// 16-deep gather pipeline, then 4, then 1.
#define ACC1(V) \
    accx += __builtin_bit_cast(float, V << 16); \
    accy += __builtin_bit_cast(float, V & 0xffff0000u);

__global__ __launch_bounds__(256) void spmm_bn_relu4(
    const uint* __restrict__ Hs, const int* __restrict__ cols,
    const int* __restrict__ rowptr, const float* __restrict__ dinv,
    const float* __restrict__ s, const float* __restrict__ t,
    float* __restrict__ Y) {
    const int lane = threadIdx.x & 63;
    const int r = blockIdx.x * 4 + (threadIdx.x >> 6);

    uint vself = Hs[(size_t)r * 64 + lane];
    float accx = __builtin_bit_cast(float, vself << 16);
    float accy = __builtin_bit_cast(float, vself & 0xffff0000u);
    const float di = dinv[r];
    const int e0 = rowptr[r], e1 = rowptr[r + 1];
    int j = e0;
    const int n16 = e0 + ((e1 - e0) & ~15);
    for (; j < n16; j += 16) {
        uint v[16];
        #pragma unroll
        for (int q = 0; q < 16; ++q)
            v[q] = Hs[(size_t)cols[j + q] * 64 + lane];
        #pragma unroll
        for (int q = 0; q < 16; ++q) { ACC1(v[q]) }
    }
    const int n4 = e0 + ((e1 - e0) & ~3);
    for (; j < n4; j += 4) {
        uint v[4];
        #pragma unroll
        for (int q = 0; q < 4; ++q)
            v[q] = Hs[(size_t)cols[j + q] * 64 + lane];
        #pragma unroll
        for (int q = 0; q < 4; ++q) { ACC1(v[q]) }
    }
    for (; j < e1; ++j) {
        uint v0 = Hs[(size_t)cols[j] * 64 + lane];
        ACC1(v0)
    }
    float2 sf = ((const float2*)s)[lane];
    float2 tf = ((const float2*)t)[lane];
    float2 o;
    o.x = fmaxf(fmaf(accx * di, sf.x, tf.x), 0.0f);
    o.y = fmaxf(fmaf(accy * di, sf.y, tf.y), 0.0f);
    ((float2*)Y)[(size_t)r * 64 + lane] = o;
}

// -------------------- final FC: out = [x0|x1|x2] @ fcW + fcb  (384 -> 40)
// v11: NO LDS, NO BARRIERS. v6/v7/v10 all hit ~102us despite structurally
// different staging schedules and even 2x different FMA counts -> the
// chunk-serialized {global->reg->LDS->barrier->compute} structure itself
// was the wall, and LDS bought nothing: each staged element is read back
// by exactly one wave (no cross-wave LDS reuse; the 4 col-group waves
// share X cachelines through L1 instead). Here each wave streams its 64
// rows straight from global, float4/lane per k4-step, FMAs into acc[10];
// W stays scalarized via readfirstlane (uniform -> s_load, const cache).
// Waves are fully independent: TLP (6 blocks/CU) + compiler load-ahead in
// a plain streaming loop hide latency -- no barrier for hipcc to drain at.
__global__ __launch_bounds__(256) void final_gemm11(
    const float* __restrict__ X0, const float* __restrict__ X1,
    const float* __restrict__ X2, const float* __restrict__ fcW,
    const float* __restrict__ fcb, float* __restrict__ out) {
    const int t = threadIdx.x;
    const int lane = t & 63;
    const int wq = __builtin_amdgcn_readfirstlane(t >> 6);  // col group, SGPR
    const int r = blockIdx.x * 64 + lane;
    if (r >= N_NODES) return;

    float acc[10];
    #pragma unroll
    for (int c = 0; c < 10; ++c) acc[c] = 0.0f;

    const float* segs[3] = {X0, X1, X2};
    #pragma unroll
    for (int seg = 0; seg < 3; ++seg) {
        const float4* xrow = (const float4*)(segs[seg] + (size_t)r * 128);
        const float* wseg = fcW + (size_t)seg * 128 * 40 + wq * 10;  // uniform
        #pragma unroll 2
        for (int k4 = 0; k4 < 32; ++k4) {
            float4 xv = xrow[k4];                 // 16B coalesced-per-row
            const float* w0 = wseg + (size_t)k4 * 160;   // s_load'd rows
            #pragma unroll
            for (int c = 0; c < 10; ++c) {
                acc[c] = fmaf(xv.x, w0[c],        acc[c]);
                acc[c] = fmaf(xv.y, w0[40 + c],   acc[c]);
                acc[c] = fmaf(xv.z, w0[80 + c],   acc[c]);
                acc[c] = fmaf(xv.w, w0[120 + c],  acc[c]);
            }
        }
    }

    #pragma unroll
    for (int c2 = 0; c2 < 5; ++c2) {
        float2 o;
        o.x = acc[c2 * 2 + 0] + fcb[wq * 10 + c2 * 2 + 0];
        o.y = acc[c2 * 2 + 1] + fcb[wq * 10 + c2 * 2 + 1];
        *(float2*)(out + (size_t)r * 40 + wq * 10 + c2 * 2) = o;
    }
}

// ---------------------------------------------------------------------------
extern "C" void kernel_launch(void* const* d_in, const int* in_sizes, int n_in,
                              void* d_out, int out_size, void* d_ws, size_t ws_size,
                              hipStream_t stream) {
    const float* x   = (const float*)d_in[0];
    const int*   ei  = (const int*)d_in[1];
    const int* e_row = ei;
    const int* e_col = ei + N_EDGES;
    const float* W1  = (const float*)d_in[2];
    const float* b1  = (const float*)d_in[3];
    const float* W2  = (const float*)d_in[4];
    const float* b2  = (const float*)d_in[5];
    const float* g1  = (const float*)d_in[6];
    const float* be1 = (const float*)d_in[7];
    const float* m1  = (const float*)d_in[8];
    const float* v1  = (const float*)d_in[9];
    const float* g2  = (const float*)d_in[10];
    const float* be2 = (const float*)d_in[11];
    const float* m2  = (const float*)d_in[12];
    const float* v2  = (const float*)d_in[13];
    const float* fcW = (const float*)d_in[14];
    const float* fcb = (const float*)d_in[15];
    float* out = (float*)d_out;

    char* ws = (char*)d_ws;
    size_t off = 0;
    auto alloc = [&](size_t b) {
        char* p = ws + off;
        off += (b + 255) & ~(size_t)255;
        return p;
    };
    uint*  h      = (uint*)alloc((size_t)N_NODES * C_H * 2);     // bf16 Hs
    float* x1     = (float*)alloc((size_t)N_NODES * C_H * 4);
    float* x2     = (float*)alloc((size_t)N_NODES * C_H * 4);
    int2*  pairs  = (int2*)alloc((size_t)N_EDGES * 8);
    int*   cols   = (int*)alloc((size_t)N_EDGES * 4);
    float* dinv   = (float*)alloc(N_NODES * 4);
    int*   rowptr = (int*)alloc((N_NODES + 1) * 4);
    int*   bcnt   = (int*)alloc((NB + 1) * 4);
    int*   bstart = (int*)alloc((NB + 1) * 4);
    int*   bfill  = (int*)alloc((NB + 1) * 4);
    float* coef   = (float*)alloc(512 * 4);
    float* s1 = coef, *t1 = coef + 128, *s2 = coef + 256, *t2 = coef + 384;

    const int nwg_bin = (N_EDGES + CHUNK - 1) / CHUNK;   // 261

    zero_i32<<<2, 256, 0, stream>>>(bcnt, NB);
    bucket_count<<<nwg_bin, 256, 0, stream>>>(e_row, bcnt);
    scan_buckets<<<1, 256, 0, stream>>>(bcnt, bstart, bfill);
    bucket_bin<<<nwg_bin, 256, 0, stream>>>(e_row, e_col, bfill, pairs);
    bucket_csr<<<NB, 256, 0, stream>>>(pairs, bstart, rowptr, dinv, cols);
    bn_coef<<<1, 128, 0, stream>>>(b1, g1, be1, m1, v1, b2, g2, be2, m2, v2,
                                   s1, t1, s2, t2);

    gemm_scaled<<<N_NODES / 32, 256, 0, stream>>>(x, W1, dinv, h);
    spmm_bn_relu4<<<N_NODES / 4, 256, 0, stream>>>(h, cols, rowptr, dinv, s1, t1, x1);
    gemm_scaled<<<N_NODES / 32, 256, 0, stream>>>(x1, W2, dinv, h);
    spmm_bn_relu4<<<N_NODES / 4, 256, 0, stream>>>(h, cols, rowptr, dinv, s2, t2, x2);
    final_gemm11<<<(N_NODES + 63) / 64, 256, 0, stream>>>(x, x1, x2, fcW, fcb, out);
}